// Round 1
// baseline (123.726 us; speedup 1.0000x reference)
//
#include <hip/hip_runtime.h>
#include <math.h>

#define Bb 2
#define Lq 512
#define CS 384
#define CZ 128
#define Hh 8
#define HD 16

__device__ inline float wave_reduce_sum(float v) {
    #pragma unroll
    for (int off = 32; off > 0; off >>= 1) v += __shfl_xor(v, off, 64);
    return v;
}
__device__ inline float wave_reduce_max(float v) {
    #pragma unroll
    for (int off = 32; off > 0; off >>= 1) v = fmaxf(v, __shfl_xor(v, off, 64));
    return v;
}

// Stage 1: x = rmsnorm(s @ W_s^T, g_s)   -> x_ws[(b*L+l)*128 + c]
__global__ __launch_bounds__(128) void k_stage1(const float* __restrict__ s,
        const float* __restrict__ W_s, const float* __restrict__ g_s,
        float* __restrict__ x_ws) {
    int row = blockIdx.x;          // b*L + l  (0..1023)
    int c = threadIdx.x;           // 0..127
    __shared__ float srow[CS];
    __shared__ float red[2];
    const float* sp = s + (size_t)row * CS;
    for (int i = c; i < CS; i += 128) srow[i] = sp[i];
    __syncthreads();
    const float4* w4 = (const float4*)(W_s + (size_t)c * CS);
    const float4* s4 = (const float4*)srow;
    float acc = 0.f;
    #pragma unroll 4
    for (int i = 0; i < CS/4; ++i) {
        float4 a = s4[i], w = w4[i];
        acc += a.x*w.x + a.y*w.y + a.z*w.z + a.w*w.w;
    }
    float ss = wave_reduce_sum(acc * acc);
    int lane = c & 63, wid = c >> 6;
    if (lane == 0) red[wid] = ss;
    __syncthreads();
    float tot = red[0] + red[1];
    float scale = rsqrtf(tot * (1.f/CZ) + 1e-5f);
    x_ws[(size_t)row * CZ + c] = acc * scale * g_s[c];
}

// Stage 2: qk = x @ W_qk^T, apply RoPE, store q/k as [half][b][h][l][16]
__global__ __launch_bounds__(256) void k_stage2(const float* __restrict__ x_ws,
        const float* __restrict__ W_qk, float* __restrict__ qk_ws) {
    int row = blockIdx.x;          // b*L + l
    int l = row & (Lq - 1);
    int b = row >> 9;
    int j = threadIdx.x;           // 0..255
    __shared__ float xrow[CZ];
    __shared__ float qkrow[2*CZ];
    if (j < CZ) xrow[j] = x_ws[(size_t)row*CZ + j];
    __syncthreads();
    const float4* w4 = (const float4*)(W_qk + (size_t)j * CZ);
    const float4* x4 = (const float4*)xrow;
    float acc = 0.f;
    #pragma unroll 4
    for (int i = 0; i < CZ/4; ++i) {
        float4 a = x4[i], w = w4[i];
        acc += a.x*w.x + a.y*w.y + a.z*w.z + a.w*w.w;
    }
    qkrow[j] = acc;
    __syncthreads();
    int half = j >> 7;             // 0 = q, 1 = k
    int within = j & 127;
    int h = within >> 4;
    int dd = within & 15;
    int d = dd >> 1;
    float xr = qkrow[j & ~1];
    float xi = qkrow[j | 1];
    float inv = powf(10000.f, -(float)(2*d) * (1.f/16.f));
    float ang = (float)l * inv;
    float cv = cosf(ang), sv = sinf(ang);
    float outv = (dd & 1) ? (xr*sv + xi*cv) : (xr*cv - xi*sv);
    size_t idx = ((((size_t)half*Bb + b)*Hh + h)*Lq + l)*HD + dd;
    qk_ws[idx] = outv;
}

// Stage 3: scores -> mask -> softmax.  attn[((b*8+h)*512+l)*512 + m]
__global__ __launch_bounds__(256) void k_stage3(const float* __restrict__ qk_ws,
        const int* __restrict__ mask, float* __restrict__ attn) {
    int bid = blockIdx.x;          // (b*8+h)*512 + l
    int l = bid & (Lq - 1);
    int bh = bid >> 9;
    int h = bh & (Hh - 1);
    int b = bh >> 3;
    int t = threadIdx.x;
    __shared__ float qrow[HD];
    __shared__ float red[4];
    const float* qbase = qk_ws + (((size_t)b*Hh + h)*Lq + l)*HD;
    if (t < HD) qrow[t] = qbase[t];
    __syncthreads();
    const float* kbase = qk_ws + (((size_t)Bb + b)*Hh + h)*Lq*HD;  // half=1
    int maskL = mask[b*Lq + l];
    float vals[2];
    int ms[2] = {t, t + 256};
    #pragma unroll
    for (int i = 0; i < 2; ++i) {
        int m = ms[i];
        const float4* k4 = (const float4*)(kbase + (size_t)m * HD);
        float acc = 0.f;
        #pragma unroll
        for (int r = 0; r < 4; ++r) {
            float4 kk = k4[r];
            float4 qq = ((const float4*)qrow)[r];
            acc += qq.x*kk.x + qq.y*kk.y + qq.z*kk.z + qq.w*kk.w;
        }
        acc *= 0.25f;                      // 1/sqrt(16)
        int pm = maskL & mask[b*Lq + m];
        vals[i] = pm ? acc : -3.4028234663852886e38f;
    }
    float mx = fmaxf(vals[0], vals[1]);
    mx = wave_reduce_max(mx);
    int lane = t & 63, wid = t >> 6;
    if (lane == 0) red[wid] = mx;
    __syncthreads();
    mx = fmaxf(fmaxf(red[0], red[1]), fmaxf(red[2], red[3]));
    float e0 = __expf(vals[0] - mx);
    float e1 = __expf(vals[1] - mx);
    float sum = wave_reduce_sum(e0 + e1);
    __syncthreads();
    if (lane == 0) red[wid] = sum;
    __syncthreads();
    sum = red[0] + red[1] + red[2] + red[3];
    float inv = 1.f / sum;
    float* arow = attn + (size_t)bid * Lq;
    arow[ms[0]] = e0 * inv;
    arow[ms[1]] = e1 * inv;
}

// Stage 4: out[b,l,m,c] = rmsnorm_c( sum_h attn[b,h,l,m] * W_o[c,h] ) * g_z
__global__ __launch_bounds__(256) void k_stage4(const float* __restrict__ attn,
        const float* __restrict__ W_o, const float* __restrict__ g_z,
        float* __restrict__ out) {
    int bid = blockIdx.x;          // (b*L + l)*4 + mblk
    int mblk = bid & 3;
    int row = bid >> 2;            // b*L + l
    int l = row & (Lq - 1);
    int b = row >> 9;
    int m0 = mblk * 128;
    int t = threadIdx.x;
    int lane = t & 63, wv = t >> 6;
    __shared__ float p_lds[Hh * 128];
    for (int idx = t; idx < Hh * 128; idx += 256) {
        int h = idx >> 7, jj = idx & 127;
        p_lds[idx] = attn[(((size_t)(b*Hh + h)*Lq + l))*Lq + m0 + jj];
    }
    int c0 = lane * 2;
    float wo0[Hh], wo1[Hh];
    {
        const float4* wp = (const float4*)(W_o + (size_t)c0 * Hh);
        float4 a0 = wp[0], a1 = wp[1], a2 = wp[2], a3 = wp[3];
        wo0[0]=a0.x; wo0[1]=a0.y; wo0[2]=a0.z; wo0[3]=a0.w;
        wo0[4]=a1.x; wo0[5]=a1.y; wo0[6]=a1.z; wo0[7]=a1.w;
        wo1[0]=a2.x; wo1[1]=a2.y; wo1[2]=a2.z; wo1[3]=a2.w;
        wo1[4]=a3.x; wo1[5]=a3.y; wo1[6]=a3.z; wo1[7]=a3.w;
    }
    float gx = g_z[c0], gy = g_z[c0 + 1];
    __syncthreads();
    float* obase = out + (((size_t)row)*Lq + m0)*CZ;
    for (int r = wv; r < 128; r += 4) {
        float p[Hh];
        #pragma unroll
        for (int h = 0; h < Hh; ++h) p[h] = p_lds[h*128 + r];
        float v0 = 0.f, v1 = 0.f;
        #pragma unroll
        for (int h = 0; h < Hh; ++h) { v0 += p[h]*wo0[h]; v1 += p[h]*wo1[h]; }
        float ss = wave_reduce_sum(v0*v0 + v1*v1);
        float sc = rsqrtf(ss * (1.f/CZ) + 1e-5f);
        float2 o; o.x = v0*sc*gx; o.y = v1*sc*gy;
        *(float2*)(obase + (size_t)r*CZ + c0) = o;
    }
}

extern "C" void kernel_launch(void* const* d_in, const int* in_sizes, int n_in,
                              void* d_out, int out_size, void* d_ws, size_t ws_size,
                              hipStream_t stream) {
    const float* s    = (const float*)d_in[0];
    const int*   mask = (const int*)d_in[1];
    const float* W_s  = (const float*)d_in[2];
    const float* g_s  = (const float*)d_in[3];
    const float* W_qk = (const float*)d_in[4];
    const float* W_o  = (const float*)d_in[5];
    const float* g_z  = (const float*)d_in[6];
    float* out = (float*)d_out;
    float* ws  = (float*)d_ws;

    // workspace layout (floats):
    //   x_ws  : [0, 131072)              = 1024*128
    //   qk_ws : [131072, 393216)         = 2*2*8*512*16
    //   attn  : [393216, 4587520)        = 2*8*512*512   (~18.4 MB total)
    float* x_ws  = ws;
    float* qk_ws = ws + 131072;
    float* attn  = ws + 393216;

    k_stage1<<<Bb*Lq, 128, 0, stream>>>(s, W_s, g_s, x_ws);
    k_stage2<<<Bb*Lq, 256, 0, stream>>>(x_ws, W_qk, qk_ws);
    k_stage3<<<Bb*Hh*Lq, 256, 0, stream>>>(qk_ws, mask, attn);
    k_stage4<<<Bb*Lq*4, 256, 0, stream>>>(attn, W_o, g_z, out);
}

// Round 2
// 92.462 us; speedup vs baseline: 1.3381x; 1.3381x over previous
//
#include <hip/hip_runtime.h>
#include <math.h>

#define Bb 2
#define Lq 512
#define CS 384
#define CZ 128
#define Hh 8
#define HD 16
#define NEG_MAX -3.4028234663852886e38f

__device__ inline float wave_reduce_sum(float v) {
    #pragma unroll
    for (int off = 32; off > 0; off >>= 1) v += __shfl_xor(v, off, 64);
    return v;
}
__device__ inline float wave_reduce_max(float v) {
    #pragma unroll
    for (int off = 32; off > 0; off >>= 1) v = fmaxf(v, __shfl_xor(v, off, 64));
    return v;
}
__device__ inline void wave_reduce_sum2(float& a, float& b) {
    #pragma unroll
    for (int off = 32; off > 0; off >>= 1) {
        a += __shfl_xor(a, off, 64);
        b += __shfl_xor(b, off, 64);
    }
}

// Stage 1: x = rmsnorm(s @ W_s^T, g_s), 4 rows per block (W_s rows read once per 4 rows)
__global__ __launch_bounds__(128) void k_stage1(const float* __restrict__ s,
        const float* __restrict__ W_s, const float* __restrict__ g_s,
        float* __restrict__ x_ws) {
    int blk = blockIdx.x;            // rows blk*4 .. blk*4+3
    int c = threadIdx.x;             // 0..127 output channel
    __shared__ float srow[4*CS];
    __shared__ float red[2][4];
    size_t base = (size_t)blk * 4 * CS;
    for (int i = c; i < 4*CS; i += 128) srow[i] = s[base + i];
    __syncthreads();
    const float4* w4 = (const float4*)(W_s + (size_t)c * CS);
    const float4* s0 = (const float4*)(srow);
    const float4* s1 = (const float4*)(srow + CS);
    const float4* s2 = (const float4*)(srow + 2*CS);
    const float4* s3 = (const float4*)(srow + 3*CS);
    float a0=0.f, a1=0.f, a2=0.f, a3=0.f;
    #pragma unroll 4
    for (int i = 0; i < CS/4; ++i) {
        float4 w = w4[i];
        float4 v0=s0[i], v1=s1[i], v2=s2[i], v3=s3[i];
        a0 += w.x*v0.x + w.y*v0.y + w.z*v0.z + w.w*v0.w;
        a1 += w.x*v1.x + w.y*v1.y + w.z*v1.z + w.w*v1.w;
        a2 += w.x*v2.x + w.y*v2.y + w.z*v2.z + w.w*v2.w;
        a3 += w.x*v3.x + w.y*v3.y + w.z*v3.z + w.w*v3.w;
    }
    float s00=a0*a0, s11=a1*a1, s22=a2*a2, s33=a3*a3;
    wave_reduce_sum2(s00, s11);
    wave_reduce_sum2(s22, s33);
    int lane = c & 63, wid = c >> 6;
    if (lane == 0) { red[wid][0]=s00; red[wid][1]=s11; red[wid][2]=s22; red[wid][3]=s33; }
    __syncthreads();
    float g = g_s[c];
    float t0 = red[0][0]+red[1][0];
    float t1 = red[0][1]+red[1][1];
    float t2 = red[0][2]+red[1][2];
    float t3 = red[0][3]+red[1][3];
    size_t ob = (size_t)blk * 4 * CZ + c;
    x_ws[ob        ] = a0 * rsqrtf(t0*(1.f/CZ) + 1e-5f) * g;
    x_ws[ob +   CZ ] = a1 * rsqrtf(t1*(1.f/CZ) + 1e-5f) * g;
    x_ws[ob + 2*CZ ] = a2 * rsqrtf(t2*(1.f/CZ) + 1e-5f) * g;
    x_ws[ob + 3*CZ ] = a3 * rsqrtf(t3*(1.f/CZ) + 1e-5f) * g;
}

// Stage 2: qk = x @ W_qk^T + RoPE, 4 rows per block. q/k stored [half][b][h][l][16]
__global__ __launch_bounds__(256) void k_stage2(const float* __restrict__ x_ws,
        const float* __restrict__ W_qk, float* __restrict__ qk_ws) {
    int blk = blockIdx.x;            // rows blk*4 .. blk*4+3
    int j = threadIdx.x;             // 0..255 qk channel
    __shared__ float xrow[4*CZ];
    __shared__ float qkrow[4][2*CZ];
    size_t base = (size_t)blk * 4 * CZ;
    for (int i = j; i < 4*CZ; i += 256) xrow[i] = x_ws[base + i];
    __syncthreads();
    const float4* w4 = (const float4*)(W_qk + (size_t)j * CZ);
    const float4* x0 = (const float4*)(xrow);
    const float4* x1 = (const float4*)(xrow + CZ);
    const float4* x2 = (const float4*)(xrow + 2*CZ);
    const float4* x3 = (const float4*)(xrow + 3*CZ);
    float a0=0.f, a1=0.f, a2=0.f, a3=0.f;
    #pragma unroll 4
    for (int i = 0; i < CZ/4; ++i) {
        float4 w = w4[i];
        float4 v0=x0[i], v1=x1[i], v2=x2[i], v3=x3[i];
        a0 += w.x*v0.x + w.y*v0.y + w.z*v0.z + w.w*v0.w;
        a1 += w.x*v1.x + w.y*v1.y + w.z*v1.z + w.w*v1.w;
        a2 += w.x*v2.x + w.y*v2.y + w.z*v2.z + w.w*v2.w;
        a3 += w.x*v3.x + w.y*v3.y + w.z*v3.z + w.w*v3.w;
    }
    qkrow[0][j]=a0; qkrow[1][j]=a1; qkrow[2][j]=a2; qkrow[3][j]=a3;
    __syncthreads();
    int half = j >> 7, within = j & 127, h = within >> 4, dd = within & 15, d = dd >> 1;
    int row0 = blk * 4;
    int b = row0 >> 9;
    float inv = powf(10000.f, -(float)(2*d) * (1.f/16.f));
    #pragma unroll
    for (int r = 0; r < 4; ++r) {
        int l = (row0 + r) & (Lq - 1);
        float ang = (float)l * inv;
        float cv = cosf(ang), sn = sinf(ang);
        float xr = qkrow[r][j & ~1];
        float xi = qkrow[r][j | 1];
        float outv = (dd & 1) ? (xr*sn + xi*cv) : (xr*cv - xi*sn);
        size_t idx = ((((size_t)half*Bb + b)*Hh + h)*Lq + l)*HD + dd;
        qk_ws[idx] = outv;
    }
}

// Fused stage 3+4: per (b,l) block. Wave w computes softmax row for head w into LDS,
// then all 8 waves produce out[b,l,:,:] (512 rows x 128 ch) with rmsnorm over ch.
__global__ __launch_bounds__(512) void k_attn(const float* __restrict__ qk_ws,
        const int* __restrict__ mask, const float* __restrict__ W_o,
        const float* __restrict__ g_z, float* __restrict__ out) {
    int row = blockIdx.x;            // b*512 + l
    int l = row & (Lq - 1);
    int b = row >> 9;
    int t = threadIdx.x;
    int w = t >> 6, lane = t & 63;
    __shared__ float p_lds[Hh][Lq];  // 16 KB softmax probs
    __shared__ float q_lds[CZ];
    if (t < CZ) {
        int qh = t >> 4, dd = t & 15;
        q_lds[t] = qk_ws[(((size_t)b*Hh + qh)*Lq + l)*HD + dd];
    }
    int maskL = mask[b*Lq + l];
    __syncthreads();

    // ---- phase 1: wave w == head h ----
    int h = w;
    const float* kbase = qk_ws + ((((size_t)Bb + b)*Hh + h)*Lq)*HD;
    float q[HD];
    #pragma unroll
    for (int d = 0; d < HD; ++d) q[d] = q_lds[h*HD + d];
    float sv[8];
    float mx = NEG_MAX;
    #pragma unroll
    for (int i = 0; i < 8; ++i) {
        int m = i*64 + lane;
        const float4* k4 = (const float4*)(kbase + (size_t)m * HD);
        float4 k0=k4[0], k1=k4[1], k2=k4[2], k3=k4[3];
        float acc = q[0]*k0.x + q[1]*k0.y + q[2]*k0.z + q[3]*k0.w
                  + q[4]*k1.x + q[5]*k1.y + q[6]*k1.z + q[7]*k1.w
                  + q[8]*k2.x + q[9]*k2.y + q[10]*k2.z + q[11]*k2.w
                  + q[12]*k3.x + q[13]*k3.y + q[14]*k3.z + q[15]*k3.w;
        int pm = maskL & mask[b*Lq + m];
        sv[i] = pm ? acc*0.25f : NEG_MAX;
        mx = fmaxf(mx, sv[i]);
    }
    mx = wave_reduce_max(mx);
    float e[8];
    float sum = 0.f;
    #pragma unroll
    for (int i = 0; i < 8; ++i) { e[i] = __expf(sv[i]-mx); sum += e[i]; }
    sum = wave_reduce_sum(sum);
    float inv = 1.f / sum;
    #pragma unroll
    for (int i = 0; i < 8; ++i) p_lds[h][i*64+lane] = e[i]*inv;

    // ---- phase 2: output 512 rows x 128 ch ----
    int c0 = lane * 2;
    float wo0[Hh], wo1[Hh];
    {
        const float4* wp = (const float4*)(W_o + (size_t)c0 * Hh);
        float4 A0=wp[0], A1=wp[1], A2=wp[2], A3=wp[3];
        wo0[0]=A0.x; wo0[1]=A0.y; wo0[2]=A0.z; wo0[3]=A0.w;
        wo0[4]=A1.x; wo0[5]=A1.y; wo0[6]=A1.z; wo0[7]=A1.w;
        wo1[0]=A2.x; wo1[1]=A2.y; wo1[2]=A2.z; wo1[3]=A2.w;
        wo1[4]=A3.x; wo1[5]=A3.y; wo1[6]=A3.z; wo1[7]=A3.w;
    }
    float gx = g_z[c0], gy = g_z[c0 + 1];
    __syncthreads();
    float* obase = out + (size_t)row * Lq * CZ;
    #pragma unroll 1
    for (int i = 0; i < 64; i += 2) {
        int m0 = (i  )*8 + w;        // waves write adjacent rows each iteration
        int m1 = (i+1)*8 + w;
        float p0[Hh], p1[Hh];
        #pragma unroll
        for (int k = 0; k < Hh; ++k) { p0[k]=p_lds[k][m0]; p1[k]=p_lds[k][m1]; }
        float a0=0.f, b0=0.f, a1=0.f, b1=0.f;
        #pragma unroll
        for (int k = 0; k < Hh; ++k) {
            a0 += p0[k]*wo0[k]; b0 += p0[k]*wo1[k];
            a1 += p1[k]*wo0[k]; b1 += p1[k]*wo1[k];
        }
        float ss0 = a0*a0 + b0*b0;
        float ss1 = a1*a1 + b1*b1;
        wave_reduce_sum2(ss0, ss1);
        float sc0 = rsqrtf(ss0*(1.f/CZ) + 1e-5f);
        float sc1 = rsqrtf(ss1*(1.f/CZ) + 1e-5f);
        float2 o0; o0.x = a0*sc0*gx; o0.y = b0*sc0*gy;
        float2 o1; o1.x = a1*sc1*gx; o1.y = b1*sc1*gy;
        *(float2*)(obase + (size_t)m0*CZ + c0) = o0;
        *(float2*)(obase + (size_t)m1*CZ + c0) = o1;
    }
}

extern "C" void kernel_launch(void* const* d_in, const int* in_sizes, int n_in,
                              void* d_out, int out_size, void* d_ws, size_t ws_size,
                              hipStream_t stream) {
    const float* s    = (const float*)d_in[0];
    const int*   mask = (const int*)d_in[1];
    const float* W_s  = (const float*)d_in[2];
    const float* g_s  = (const float*)d_in[3];
    const float* W_qk = (const float*)d_in[4];
    const float* W_o  = (const float*)d_in[5];
    const float* g_z  = (const float*)d_in[6];
    float* out = (float*)d_out;
    float* ws  = (float*)d_ws;

    // workspace (floats): x_ws [0,131072), qk_ws [131072, 393216)
    float* x_ws  = ws;
    float* qk_ws = ws + 131072;

    k_stage1<<<256, 128, 0, stream>>>(s, W_s, g_s, x_ws);
    k_stage2<<<256, 256, 0, stream>>>(x_ws, W_qk, qk_ws);
    k_attn<<<Bb*Lq, 512, 0, stream>>>(qk_ws, mask, W_o, g_z, out);
}